// Round 25
// baseline (71.726 us; speedup 1.0000x reference)
//
#include <hip/hip_runtime.h>

#define NB    8
#define NH    16384
#define NL    2048
#define F_HR  64
#define F_LR  128
#define OUT_COLS 198   // 64 + 3 + 128 + 3

// IEEE-f32 -> uint key, order-preserving and BIJECTIVE (proven R22):
// key-min == float-min, key-equality == bit-equality.
__device__ __forceinline__ unsigned fkey(float v) {
    unsigned b = __float_as_uint(v);
    return b ^ ((unsigned)((int)b >> 31) | 0x80000000u);
}
__device__ __forceinline__ float fdec(unsigned k) {
    unsigned b = (k & 0x80000000u) ? (k ^ 0x80000000u) : ~k;
    return __uint_as_float(b);
}

// ---------------------------------------------------------------------------
// R25: the last untested cell of the {waves/SIMD x pairs-per-read} grid.
// Model (R24 recalibration, m134 constants): scan = LDS 20.5us + VALU 13.6us;
// at 4 waves/SIMD they SERIALIZE (measured ~40us, both pipes ~52%); R22's
// 8 waves/SIMD doubled reads (M=2). Here: 1024-thr knn blocks (16 waves),
// 256 points (M=4/lane unchanged -> 256 pairs/read unchanged), 16 slices x
// 128 cands; LDS 43KB via atomicMin-key merge -> 2 blocks/CU = 8 waves/SIMD.
// Blocks [0,512): knn + fused gather of cols 67..197.
//   Phase A: value-only min3 scan (key formula text identical since R3,
//     bit-exact across 20 passing rounds); slice min -> ds_min_u32 on key.
//   Phase B: key==gmin -> atomicMin(winw, w): lowest slice = first occur.
//   Phase C: per-wave compact (uchar plist) + rescue rescan (2 cands/lane).
//   Phase D: phase-split gather, e-linear 256x131, 3 batches of 11.
// Blocks [512,640): idx-independent copy (1024 rows cols 0..66 + tail).
// ---------------------------------------------------------------------------
__global__ __launch_bounds__(1024, 8) void fused_kernel(
    const float* __restrict__ pos_hr,   // [NB*NH, 3]
    const float* __restrict__ pos_lr,   // [NB*NL, 3]
    const float* __restrict__ x_hr,     // [NB*NH, 64]
    const float* __restrict__ x_lr,     // [NB*NL, 128]
    float* __restrict__ out)
{
    __shared__ float4        cand[NL];        // 32 KiB (x, y, z, 0.5*|p|^2)
    __shared__ unsigned      gmin[256];       //  1 KiB global min KEY per point
    __shared__ int           winw[256];       //  1 KiB winning slice per point
    __shared__ unsigned char plist[16][256];  //  4 KiB per-wave compacted points
    __shared__ float         phsx[256], phsy[256], phsz[256];  // 3 KiB staged ph
    __shared__ int           s_idx[256];      //  1 KiB winner (global lr row)

    const int tid = threadIdx.x;

    if (blockIdx.x < 512) {
        // ----------------------------- knn role -----------------------------
        const int b  = blockIdx.x >> 6;     // 64 blocks per batch
        const int p0 = blockIdx.x << 8;     // first global point (256/block)
        const int w  = tid >> 6;            // wave id = candidate slice [0,16)
        const int l  = tid & 63;

        const float* pl = pos_lr + (size_t)b * NL * 3;
        for (int j = tid; j < NL; j += 1024) {
            float x = pl[j * 3 + 0];
            float y = pl[j * 3 + 1];
            float z = pl[j * 3 + 2];
            cand[j] = make_float4(x, y, z, 0.5f * ((x * x + y * y) + z * z));
        }
        if (tid < 256) {
            gmin[tid] = 0xFFFFFFFFu;
            winw[tid] = 16;
        }

        // M=4 points per lane (every wave covers all 256 block points)
        float phx[4], phy[4], phz[4];
#pragma unroll
        for (int m = 0; m < 4; ++m) {
            const int pt = p0 + (m << 6) + l;
            phx[m] = pos_hr[pt * 3 + 0];
            phy[m] = pos_hr[pt * 3 + 1];
            phz[m] = pos_hr[pt * 3 + 2];
        }
        if (w == 0) {                        // stage ph for the rescue phase
#pragma unroll
            for (int m = 0; m < 4; ++m) {
                const int ptl = (m << 6) + l;
                phsx[ptl] = phx[m]; phsy[ptl] = phy[m]; phsz[ptl] = phz[m];
            }
        }
        __syncthreads();

        // Phase A: value-only min3 scan over this wave's 128-cand slice
        float best[4];
#pragma unroll
        for (int m = 0; m < 4; ++m) best[m] = 3.4e38f;

        const int base = w << 7;            // slice start (batch-local)
#pragma unroll 4
        for (int j = 0; j < 128; j += 2) {
            const float4 c0 = cand[base + j];
            const float4 c1 = cand[base + j + 1];
#pragma unroll
            for (int m = 0; m < 4; ++m) {
                float d0 = fmaf(-phz[m], c0.z, fmaf(-phy[m], c0.y, fmaf(-phx[m], c0.x, c0.w)));
                float d1 = fmaf(-phz[m], c1.z, fmaf(-phy[m], c1.y, fmaf(-phx[m], c1.x, c1.w)));
                best[m] = fminf(fminf(d0, d1), best[m]);   // -> v_min3_f32
            }
        }

        unsigned key[4];
#pragma unroll
        for (int m = 0; m < 4; ++m) {
            key[m] = fkey(best[m]);
            atomicMin(&gmin[(m << 6) + l], key[m]);        // exact min merge
        }
        __syncthreads();

        // Phase B: winner slice = lowest w whose key equals the global min
#pragma unroll
        for (int m = 0; m < 4; ++m) {
            const int pt = (m << 6) + l;
            if (key[m] == gmin[pt]) atomicMin(&winw[pt], w);
        }
        __syncthreads();

        // Phase C: compact points this wave won, then index-rescue scan
        int cnt = 0;
#pragma unroll
        for (int m = 0; m < 4; ++m) {
            const int pt = (m << 6) + l;
            const bool pred = (winw[pt] == w);
            const unsigned long long mask = __ballot(pred);
            const int pos = __popcll(mask & ((1ull << l) - 1ull));
            if (pred) plist[w][cnt + pos] = (unsigned char)pt;
            cnt += __popcll(mask);
        }

        for (int i = 0; i < cnt; ++i) {
            const int pt = plist[w][i];
            const float qx = phsx[pt], qy = phsy[pt], qz = phsz[pt];
            const float g  = fdec(gmin[pt]);
            // lane l covers cands base+2l, base+2l+1 (ascending)
            int loc = 2;
#pragma unroll
            for (int k = 1; k >= 0; --k) {      // descending: final loc = lowest k
                const float4 c = cand[base + (l << 1) + k];
                const float d = fmaf(-qz, c.z, fmaf(-qy, c.y, fmaf(-qx, c.x, c.w)));
                if (d == g) loc = k;            // bit-exact recompute
            }
            const unsigned long long mk = __ballot(loc < 2);
            if (mk) {
                const int firstlane = __ffsll((unsigned long long)mk) - 1;
                const int locf = __shfl(loc, firstlane);
                if (l == 0)
                    s_idx[pt] = b * NL + base + (firstlane << 1) + locf;
            }
        }
        __syncthreads();

        // Phase D: gather cols 67..197 for rows p0..p0+255.
        // 256*131 = 33536 elems, stride 1024: 33 slots = 3 batches of 11;
        // decode advance: 1024 = 7*131 + 107. Last slot valid iff tid < 768.
        {
            int rl = tid / 131;                 // tid<1024 -> rl<8
            int c  = tid - rl * 131;
            for (int t = 0; t < 3; ++t) {
                int rs[11], cs[11], ls[11];
                float vs[11];
#pragma unroll
                for (int k = 0; k < 11; ++k) {
                    rs[k] = rl; cs[k] = c;
                    ls[k] = s_idx[rl < 256 ? rl : 255];
                    c += 107;
                    const int carry = (c >= 131) ? 1 : 0;
                    c -= carry ? 131 : 0;
                    rl += 7 + carry;
                }
#pragma unroll
                for (int k = 0; k < 11; ++k) {
                    const int cc = cs[k];
                    const float* a = (cc < F_LR) ? x_lr   + ls[k] * F_LR + cc
                                                 : pos_lr + ls[k] * 3    + (cc - F_LR);
                    vs[k] = *a;
                }
#pragma unroll
                for (int k = 0; k < 11; ++k) {
                    if (t == 2 && k == 10 && tid >= 768) continue;  // e >= 33536
                    out[(size_t)(p0 + rs[k]) * OUT_COLS + 67 + cs[k]] = vs[k];
                }
            }
        }
    } else {
        // ----------------------------- copy role ----------------------------
        const int cb = blockIdx.x - 512;    // [0,128)
        const int r0 = cb << 10;            // 1024 rows per block

#pragma unroll 4
        for (int e = tid; e < 1024 * 67; e += 1024) {
            const int rl  = e / 67;
            const int c   = e - rl * 67;
            const int row = r0 + rl;
            const float v = (c < F_HR) ? x_hr[(row << 6) + c]
                                       : pos_hr[row * 3 + (c - F_HR)];
            out[row * OUT_COLS + c] = v;
        }

        const int R0 = NB * NH * OUT_COLS;  // 25,952,256
        const int Z  = NB * NH * 3;         // 393,216
        const int z0 = cb << 12;            // 4096 tail elems per block
#pragma unroll
        for (int e = tid; e < 4096; e += 1024) {
            const int i = z0 + e;
            out[R0 + i] = (i < Z) ? 0.0f : (float)((i - Z) >> 14);  // NH = 2^14
        }
    }
}

extern "C" void kernel_launch(void* const* d_in, const int* in_sizes, int n_in,
                              void* d_out, int out_size, void* d_ws, size_t ws_size,
                              hipStream_t stream) {
    const float* x_hr   = (const float*)d_in[0];
    const float* pos_hr = (const float*)d_in[1];
    // d_in[2] = batch_hr (int32) — unused, batch is contiguous repeats
    const float* x_lr   = (const float*)d_in[3];
    const float* pos_lr = (const float*)d_in[4];
    // d_in[5] = batch_lr (int32) — unused

    fused_kernel<<<dim3(640), dim3(1024), 0, stream>>>(
        pos_hr, pos_lr, x_hr, x_lr, (float*)d_out);
}

// Round 26
// 54.227 us; speedup vs baseline: 1.3227x; 1.3227x over previous
//
#include <hip/hip_runtime.h>

#define NB    8
#define NH    16384
#define NL    2048
#define F_HR  64
#define F_LR  128
#define OUT_COLS 198   // 64 + 3 + 128 + 3

// ---------------------------------------------------------------------------
// FINAL: exact R20/R24 kernel (proven best: 54.3 / 55.0 us, reproduced).
// Session map (R1 144us -> R20 54.3us):
//  - knn scan: value-only min3 scan (4 ops/pair), M=4 points/lane, 8 slices,
//    4 waves/SIMD. Pinned ~40us by {LDS broadcast-read floor 20.5us + VALU
//    13.6us, serialized at this wave count}. Refuted alternatives: SMEM
//    scalarization (R9), 1-2 waves/SIMD (R10/R18), 8 waves/SIMD M=2/M=4
//    (R22/R25), pk_fma (R15), min3-alone/unroll/ping-pong (R19/20/21 null),
//    explicit dbuf (R12), grid pruning (R23: divergence, 951us).
//  - index rescue: value-only scan + bit-exact rescan of winning slice
//    (ballot/ffs first-occurrence) — enables the 4-op scan (R16).
//  - overlap: copy role rides scan's idle memory pipe (R14); gather fused
//    after in-block argmin, idx via LDS, no global idx round-trip (R17).
// Memory: 148MB @ ~2.2TB/s effective gather/scatter mix; tail ~14us exposed.
// No pipe >62% -> structural ceiling for exact-argmin kernels, not HW roofline.
// ---------------------------------------------------------------------------
__global__ __launch_bounds__(512, 4) void fused_kernel(
    const float* __restrict__ pos_hr,   // [NB*NH, 3]
    const float* __restrict__ pos_lr,   // [NB*NL, 3]
    const float* __restrict__ x_hr,     // [NB*NH, 64]
    const float* __restrict__ x_lr,     // [NB*NL, 128]
    float* __restrict__ out)
{
    __shared__ float4 cand[NL];         // 32 KiB (x, y, z, 0.5*|p|^2)
    __shared__ float  pval[8][256];     //  8 KiB per-slice min value
    __shared__ float  gminL[256];       //  1 KiB global min per point
    __shared__ int    winw[256];        //  1 KiB winning slice per point
    __shared__ short  plist[8][256];    //  4 KiB per-wave compacted points
    __shared__ float  phsx[256], phsy[256], phsz[256];   // 3 KiB staged ph
    __shared__ int    s_idx[256];       //  1 KiB final winner (global lr row)

    if (blockIdx.x < 512) {
        // ----------------------------- knn role -----------------------------
        const int b  = blockIdx.x >> 6;     // 64 blocks per batch
        const int p0 = blockIdx.x << 8;     // first global point of this block
        const int w  = threadIdx.x >> 6;    // wave id = candidate slice
        const int l  = threadIdx.x & 63;

        const float* pl = pos_lr + (size_t)b * NL * 3;
#pragma unroll
        for (int j = threadIdx.x; j < NL; j += 512) {
            float x = pl[j * 3 + 0];
            float y = pl[j * 3 + 1];
            float z = pl[j * 3 + 2];
            cand[j] = make_float4(x, y, z, 0.5f * ((x * x + y * y) + z * z));
        }

        float phx[4], phy[4], phz[4];
#pragma unroll
        for (int m = 0; m < 4; ++m) {
            const int pt = p0 + (m << 6) + l;
            phx[m] = pos_hr[pt * 3 + 0];
            phy[m] = pos_hr[pt * 3 + 1];
            phz[m] = pos_hr[pt * 3 + 2];
        }
        if (w == 0) {                        // stage ph for the rescue phase
#pragma unroll
            for (int m = 0; m < 4; ++m) {
                const int ptl = (m << 6) + l;
                phsx[ptl] = phx[m]; phsy[ptl] = phy[m]; phsz[ptl] = phz[m];
            }
        }
        __syncthreads();

        // Phase A: value-only scan, min3 accumulate, unroll 4 (8 reads/window)
        float best[4];
#pragma unroll
        for (int m = 0; m < 4; ++m) best[m] = 3.4e38f;

        const int base = w << 8;            // slice start (batch-local)
#pragma unroll 4
        for (int j = 0; j < 256; j += 2) {
            const float4 c0 = cand[base + j];
            const float4 c1 = cand[base + j + 1];
#pragma unroll
            for (int m = 0; m < 4; ++m) {
                float d0 = fmaf(-phz[m], c0.z, fmaf(-phy[m], c0.y, fmaf(-phx[m], c0.x, c0.w)));
                float d1 = fmaf(-phz[m], c1.z, fmaf(-phy[m], c1.y, fmaf(-phx[m], c1.x, c1.w)));
                best[m] = fminf(fminf(d0, d1), best[m]);   // -> v_min3_f32
            }
        }
#pragma unroll
        for (int m = 0; m < 4; ++m)
            pval[w][(m << 6) + l] = best[m];
        __syncthreads();

        // Phase B: per-point min over slices; strict < keeps lowest slice
        if (threadIdx.x < 256) {
            const int t = threadIdx.x;
            float g = pval[0][t]; int ww = 0;
#pragma unroll
            for (int q = 1; q < 8; ++q) {
                const float qv = pval[q][t];
                if (qv < g) { g = qv; ww = q; }
            }
            gminL[t] = g; winw[t] = ww;
        }
        __syncthreads();

        // Phase C: compact points this wave won, then index-rescue scan
        int cnt = 0;
#pragma unroll
        for (int m = 0; m < 4; ++m) {
            const int pt = (m << 6) + l;
            const bool pred = (winw[pt] == w);
            const unsigned long long mask = __ballot(pred);
            const int pos = __popcll(mask & ((1ull << l) - 1ull));
            if (pred) plist[w][cnt + pos] = (short)pt;
            cnt += __popcll(mask);
        }

        for (int i = 0; i < cnt; ++i) {
            const int pt = plist[w][i];
            const float qx = phsx[pt], qy = phsy[pt], qz = phsz[pt];
            const float g  = gminL[pt];
            int loc = 4;
#pragma unroll
            for (int k = 3; k >= 0; --k) {      // descending: final loc = lowest k
                const float4 c = cand[base + (l << 2) + k];
                const float d = fmaf(-qz, c.z, fmaf(-qy, c.y, fmaf(-qx, c.x, c.w)));
                if (d == g) loc = k;            // bit-exact recompute
            }
            const unsigned long long mk = __ballot(loc < 4);
            if (mk) {
                const int firstlane = __ffsll((unsigned long long)mk) - 1;
                const int locf = __shfl(loc, firstlane);
                if (l == 0)
                    s_idx[pt] = b * NL + base + (firstlane << 2) + locf;
            }
        }
        __syncthreads();

        // Phase D: gather cols 67..197 for rows p0..p0+255.
        // e-linear over 256*131 = 33536 elems; 66 = 6*11 iters; e = tid+n*512,
        // decode rl = e/131, c = e%131 incrementally (512 = 3*131 + 119).
        {
            const int tid = threadIdx.x;
            int rl = tid / 131;
            int c  = tid - rl * 131;
            for (int t = 0; t < 11; ++t) {
                int rs[6], cs[6], ls[6];
                float vs[6];
#pragma unroll
                for (int k = 0; k < 6; ++k) {
                    rs[k] = rl; cs[k] = c;
                    ls[k] = s_idx[rl < 256 ? rl : 255];
                    c += 119;
                    const int carry = (c >= 131) ? 1 : 0;
                    c -= carry ? 131 : 0;
                    rl += 3 + carry;
                }
#pragma unroll
                for (int k = 0; k < 6; ++k) {
                    const int cc = cs[k];
                    const float* a = (cc < F_LR) ? x_lr   + ls[k] * F_LR + cc
                                                 : pos_lr + ls[k] * 3    + (cc - F_LR);
                    vs[k] = *a;
                }
#pragma unroll
                for (int k = 0; k < 6; ++k) {
                    if (t == 10 && k == 5 && tid + 33280 >= 33536) continue;  // guard
                    out[(size_t)(p0 + rs[k]) * OUT_COLS + 67 + cs[k]] = vs[k];
                }
            }
        }
    } else {
        // ----------------------------- copy role ----------------------------
        const int cb = blockIdx.x - 512;    // [0,256)
        const int r0 = cb << 9;             // 512 rows per block

#pragma unroll 4
        for (int e = threadIdx.x; e < 512 * 67; e += 512) {
            const int rl  = e / 67;
            const int c   = e - rl * 67;
            const int row = r0 + rl;
            const float v = (c < F_HR) ? x_hr[(row << 6) + c]
                                       : pos_hr[row * 3 + (c - F_HR)];
            out[row * OUT_COLS + c] = v;
        }

        const int R0 = NB * NH * OUT_COLS;  // 25,952,256
        const int Z  = NB * NH * 3;         // 393,216
        const int z0 = cb << 11;
#pragma unroll
        for (int e = threadIdx.x; e < 2048; e += 512) {
            const int i = z0 + e;
            out[R0 + i] = (i < Z) ? 0.0f : (float)((i - Z) >> 14);  // NH = 2^14
        }
    }
}

extern "C" void kernel_launch(void* const* d_in, const int* in_sizes, int n_in,
                              void* d_out, int out_size, void* d_ws, size_t ws_size,
                              hipStream_t stream) {
    const float* x_hr   = (const float*)d_in[0];
    const float* pos_hr = (const float*)d_in[1];
    // d_in[2] = batch_hr (int32) — unused, batch is contiguous repeats
    const float* x_lr   = (const float*)d_in[3];
    const float* pos_lr = (const float*)d_in[4];
    // d_in[5] = batch_lr (int32) — unused

    fused_kernel<<<dim3(768), dim3(512), 0, stream>>>(
        pos_hr, pos_lr, x_hr, x_lr, (float*)d_out);
}